// Round 2
// baseline (610.931 us; speedup 1.0000x reference)
//
#include <hip/hip_runtime.h>

// ALSH conv setup: hash kernels, vote via 1-channel conv, histogram, argmax,
// gather active kernel set.
#define O_CH   256      // out_channels
#define C_CH   64       // in_channels
#define FLATK  576      // C*K*K
#define M_TERMS 9
#define AL     585      // D*K*K = (C + 1)*9
#define TSZ    8192     // table size
#define RADIUS 4.0f
#define NB     16
#define HH     256
#define WW     256

// workspace layout (ints):
//   [0, 256)            k_idx : bucket of each kernel
//   [256, 256+8192)     hist  : vote histogram
//   [8448, 8450)        best  : 64-bit argmax key (count<<13 | (8191-idx))
//   [8450, 8450+512)    rows  : active kernel ids (-1 = empty slot)
#define WS_KIDX 0
#define WS_HIST 256
#define WS_BEST (256 + TSZ)
#define WS_ROWS (256 + TSZ + 2)

// ---------------- K1: hash kernels (1 wave per kernel) + zero histogram ----
__global__ __launch_bounds__(256) void k_init(const float* __restrict__ kernels,
                                              const float* __restrict__ a,
                                              const float* __restrict__ b,
                                              int* __restrict__ ws) {
    if (blockIdx.x < 64) {
        const int wv = threadIdx.x >> 6, lane = threadIdx.x & 63;
        const int o = blockIdx.x * 4 + wv;
        const float* wp = kernels + o * FLATK;
        float dot = 0.f, n2 = 0.f;
        #pragma unroll
        for (int j0 = 0; j0 < FLATK; j0 += 64) {   // 576/64 = 9 coalesced rounds
            float x = wp[j0 + lane];
            dot += x * a[j0 + lane];
            n2  += x * x;
        }
        #pragma unroll
        for (int off = 32; off > 0; off >>= 1) {
            dot += __shfl_xor(dot, off);
            n2  += __shfl_xor(n2, off);
        }
        if (lane == 0) {
            float p = n2, d = dot;
            for (int i = 0; i < M_TERMS; ++i) { d += p * a[FLATK + i]; p *= n2; }
            float hk = floorf((d + b[0]) / RADIUS);
            ws[WS_KIDX + o] = (int)fabsf(fmodf(hk, (float)TSZ));
        }
    } else {
        int t = (blockIdx.x - 64) * 256 + threadIdx.x;
        ws[WS_HIST + t] = 0;
        if (blockIdx.x == 64 && threadIdx.x < 2) ws[WS_BEST + threadIdx.x] = 0;
    }
}

// ---------------- K2: fused vote conv, TILE_H=8, 512 threads --------------
// Block: 512 threads = 8 waves; each wave owns ONE 256-px row (4 px/lane).
// Grid 512 -> 2 blocks/CU -> 16 waves/CU for latency hiding.
// Halo columns loaded DIRECTLY from global (same cache lines as the float4;
// L1-hit) instead of __shfl: removes the per-iteration ds_bpermute latency
// chain (load -> shuffle -> FMA was serial, ~400cyc/iter). All loads are in
// the dist-2 prefetch rotation -> only FMAs remain on the critical path.
#define TILE_H 8
__global__ __launch_bounds__(512, 4) void k_vote(const float* __restrict__ input,
                                                 const float* __restrict__ a,
                                                 const float* __restrict__ b,
                                                 int* __restrict__ ws) {
    __shared__ int   hist_s[TSZ];   // 32 KB
    __shared__ float a_s[AL];
    const int tid = threadIdx.x;

    for (int i = tid; i < TSZ; i += 512) hist_s[i] = 0;
    for (int i = tid; i < AL; i += 512) a_s[i] = a[i];
    __syncthreads();

    const float bv = b[0];
    // swizzle: xcd = blockIdx&7 gets 64 consecutive tiles (2 whole images)
    const int t   = (blockIdx.x & 7) * 64 + (blockIdx.x >> 3);
    const int by  = t & 31;                // 32 row-tiles per image
    const int n   = t >> 5;                // 16 images
    const int y0  = by * TILE_H;
    const int lane = tid & 63;             // wave spans full 256-px row
    const int wv  = tid >> 6;              // 8 waves = 8 rows
    const int x4  = lane * 4;              // columns x4..x4+3
    const int y   = y0 + wv;               // output row

    float acc[4] = {0.f, 0.f, 0.f, 0.f};
    const float* imgbase = input + (size_t)n * C_CH * HH * WW;
    const bool hasL = (lane > 0), hasR = (lane < 63);

    float4 vbuf[4][3];          // center 4 px
    float  lbuf[4][3];          // halo x4-1
    float  rbuf[4][3];          // halo x4+4

    #pragma unroll
    for (int cc = 0; cc < 2; ++cc) {       // preload channels 0,1
        const float* src = imgbase + (size_t)cc * (HH * WW);
        #pragma unroll
        for (int r = 0; r < 3; ++r) {      // input rows y-1 .. y+1
            int gy = y - 1 + r;
            bool ok = (gy >= 0 && gy < HH);
            const float* rp = src + gy * WW;
            vbuf[cc][r] = ok ? *(const float4*)(rp + x4)
                             : make_float4(0.f, 0.f, 0.f, 0.f);
            lbuf[cc][r] = (ok && hasL) ? rp[x4 - 1] : 0.f;
            rbuf[cc][r] = (ok && hasR) ? rp[x4 + 4] : 0.f;
        }
    }

    #pragma unroll 4
    for (int c = 0; c < C_CH; ++c) {
        const int cur = c & 3;
        if (c + 2 < C_CH) {                // prefetch 2 channels ahead
            const float* src = imgbase + (size_t)(c + 2) * (HH * WW);
            const int nx = (c + 2) & 3;
            #pragma unroll
            for (int r = 0; r < 3; ++r) {
                int gy = y - 1 + r;
                bool ok = (gy >= 0 && gy < HH);
                const float* rp = src + gy * WW;
                vbuf[nx][r] = ok ? *(const float4*)(rp + x4)
                                 : make_float4(0.f, 0.f, 0.f, 0.f);
                lbuf[nx][r] = (ok && hasL) ? rp[x4 - 1] : 0.f;
                rbuf[nx][r] = (ok && hasR) ? rp[x4 + 4] : 0.f;
            }
        }
        const float* ac = a_s + c * 9;
        #pragma unroll
        for (int r = 0; r < 3; ++r) {      // r == ky
            const float4 v = vbuf[cur][r];
            const float w[6] = {lbuf[cur][r], v.x, v.y, v.z, v.w, rbuf[cur][r]};
            #pragma unroll
            for (int p = 0; p < 4; ++p)
                #pragma unroll
                for (int kx = 0; kx < 3; ++kx)
                    acc[p] += w[p + kx] * ac[r * 3 + kx];
        }
    }

    // constant Q-channel (0.5 inside image, zero-padded) + vote
    {
        int gy = y;
        #pragma unroll
        for (int p = 0; p < 4; ++p) {
            int gx = x4 + p;
            float cs = 0.f;
            #pragma unroll
            for (int ky = 0; ky < 3; ++ky) {
                int yy = gy + ky - 1;
                if (yy < 0 || yy >= HH) continue;
                #pragma unroll
                for (int kx = 0; kx < 3; ++kx) {
                    int xx = gx + kx - 1;
                    if (xx < 0 || xx >= WW) continue;
                    cs += a_s[FLATK + ky * 3 + kx];
                }
            }
            float tt = acc[p] + 0.5f * cs;
            float v = floorf((tt + bv) / RADIUS);
            int vi = (int)fabsf(fmodf(v, (float)TSZ));
            atomicAdd(&hist_s[vi], 1);
        }
    }

    __syncthreads();
    int* hist_g = ws + WS_HIST;
    for (int i = tid; i < TSZ; i += 512) {
        int v = hist_s[i];
        if (v) atomicAdd(&hist_g[i], v);
    }
}

// ---------------- K3: parallel argmax (32 blocks) + count output ----------
// key = count<<13 | (8191 - idx): max key => max count, tie => smallest idx
// (matches jnp.argmax first-occurrence semantics).
__global__ __launch_bounds__(256) void k_argmax(const int* __restrict__ ws,
                                                int* __restrict__ wsbest,
                                                float* __restrict__ out) {
    const int tid = threadIdx.x;
    const int t = blockIdx.x * 256 + tid;
    const int v = ws[WS_HIST + t];
    out[512 * FLATK + t] = (float)v;      // count output (coalesced)

    unsigned long long key =
        ((unsigned long long)(unsigned)v << 13) | (unsigned)(TSZ - 1 - t);
    #pragma unroll
    for (int off = 32; off > 0; off >>= 1) {
        unsigned long long o = __shfl_xor(key, off);
        if (o > key) key = o;
    }
    __shared__ unsigned long long wk[4];
    const int lane = tid & 63, wvi = tid >> 6;
    if (lane == 0) wk[wvi] = key;
    __syncthreads();
    if (tid == 0) {
        unsigned long long k = wk[0];
        for (int i = 1; i < 4; ++i) if (wk[i] > k) k = wk[i];
        atomicMax((unsigned long long*)(wsbest + WS_BEST), k);
    }
}

// ---------------- K3b: decode best, index output, active row list ---------
__global__ __launch_bounds__(256) void k_rows(int* __restrict__ ws,
                                              float* __restrict__ out) {
    __shared__ int wsum[4];
    const int tid = threadIdx.x;
    const unsigned long long key = *(const unsigned long long*)(ws + WS_BEST);
    const int bestIdx = (TSZ - 1) - (int)(key & (unsigned long long)(TSZ - 1));
    if (tid == 0) out[512 * FLATK + TSZ] = (float)bestIdx;

    // active rows via ballot prefix-scan (insertion order = ascending id)
    int* rows = ws + WS_ROWS;
    for (int i = tid; i < 2 * O_CH; i += 256) rows[i] = -1;
    const int o = tid;
    const int match = (ws[WS_KIDX + o] == bestIdx) ? 1 : 0;
    unsigned long long m = __ballot(match);
    const int lane = tid & 63, wvi = tid >> 6;
    if (lane == 0) wsum[wvi] = __popcll(m);
    __syncthreads();   // also orders the -1 fill before the scatter
    int prefix = 0;
    for (int i = 0; i < wvi; ++i) prefix += wsum[i];
    int before = __popcll(m & ((1ull << lane) - 1ull));
    if (match) rows[prefix + before] = o;
}

// ---------------- K4: gather active kernels (float4) ----------------
__global__ __launch_bounds__(256) void k_gather(const float* __restrict__ kernels,
                                                const int* __restrict__ ws,
                                                float* __restrict__ out) {
    int gid = blockIdx.x * 256 + threadIdx.x;        // 512*144 = 73728 total
    if (gid >= 2 * O_CH * (FLATK / 4)) return;
    int s = gid / (FLATK / 4);
    int j = gid - s * (FLATK / 4);
    int r = ws[WS_ROWS + s];
    float4 v = (r >= 0) ? *(const float4*)(kernels + r * FLATK + j * 4)
                        : make_float4(0.f, 0.f, 0.f, 0.f);
    *((float4*)out + gid) = v;
}

extern "C" void kernel_launch(void* const* d_in, const int* in_sizes, int n_in,
                              void* d_out, int out_size, void* d_ws, size_t ws_size,
                              hipStream_t stream) {
    const float* input   = (const float*)d_in[0];
    const float* kernels = (const float*)d_in[1];
    const float* a       = (const float*)d_in[2];
    const float* b       = (const float*)d_in[3];
    float* out = (float*)d_out;
    int*   ws  = (int*)d_ws;

    k_init<<<96, 256, 0, stream>>>(kernels, a, b, ws);
    k_vote<<<NB * (HH / TILE_H), 512, 0, stream>>>(input, a, b, ws);
    k_argmax<<<TSZ / 256, 256, 0, stream>>>(ws, ws, out);
    k_rows<<<1, 256, 0, stream>>>(ws, out);
    k_gather<<<(2 * O_CH * (FLATK / 4) + 255) / 256, 256, 0, stream>>>(kernels, ws, out);
}

// Round 3
// 462.053 us; speedup vs baseline: 1.3222x; 1.3222x over previous
//
#include <hip/hip_runtime.h>

// ALSH conv setup: hash kernels, vote via 1-channel conv, histogram, argmax,
// gather active kernel set.
#define O_CH   256      // out_channels
#define C_CH   64       // in_channels
#define FLATK  576      // C*K*K
#define M_TERMS 9
#define AL     585      // D*K*K = (C + 1)*9
#define TSZ    8192     // table size
#define RADIUS 4.0f
#define NB     16
#define HH     256
#define WW     256

// workspace layout (ints):
//   [0, 256)            k_idx : bucket of each kernel
//   [256, 256+8192)     hist  : vote histogram
//   [8448, 8450)        best  : 64-bit argmax key (count<<13 | (8191-idx))
//   [8450, 8450+512)    rows  : active kernel ids (-1 = empty slot)
#define WS_KIDX 0
#define WS_HIST 256
#define WS_BEST (256 + TSZ)
#define WS_ROWS (256 + TSZ + 2)

// ---------------- K1: hash kernels (1 wave per kernel) + zero histogram ----
__global__ __launch_bounds__(256) void k_init(const float* __restrict__ kernels,
                                              const float* __restrict__ a,
                                              const float* __restrict__ b,
                                              int* __restrict__ ws) {
    if (blockIdx.x < 64) {
        const int wv = threadIdx.x >> 6, lane = threadIdx.x & 63;
        const int o = blockIdx.x * 4 + wv;
        const float* wp = kernels + o * FLATK;
        float dot = 0.f, n2 = 0.f;
        #pragma unroll
        for (int j0 = 0; j0 < FLATK; j0 += 64) {   // 576/64 = 9 coalesced rounds
            float x = wp[j0 + lane];
            dot += x * a[j0 + lane];
            n2  += x * x;
        }
        #pragma unroll
        for (int off = 32; off > 0; off >>= 1) {
            dot += __shfl_xor(dot, off);
            n2  += __shfl_xor(n2, off);
        }
        if (lane == 0) {
            float p = n2, d = dot;
            for (int i = 0; i < M_TERMS; ++i) { d += p * a[FLATK + i]; p *= n2; }
            float hk = floorf((d + b[0]) / RADIUS);
            ws[WS_KIDX + o] = (int)fabsf(fmodf(hk, (float)TSZ));
        }
    } else {
        int t = (blockIdx.x - 64) * 256 + threadIdx.x;
        ws[WS_HIST + t] = 0;
        if (blockIdx.x == 64 && threadIdx.x < 2) ws[WS_BEST + threadIdx.x] = 0;
    }
}

// ---------------- K2: fused vote conv, TILE_H=8, 512 threads --------------
// Block: 512 threads = 8 waves; each wave owns ONE 256-px row (4 px/lane).
// Grid 512 -> 2 blocks/CU -> 16 waves/CU.
// Halo columns loaded directly from global (L1-hit, same lines as the
// float4) so ALL inputs are in the dist-2 prefetch rotation; no shfl chain.
// __launch_bounds__(512, 2): hipcc treats arg2 as min blocks/CU -> 2
// blocks/CU -> 128-VGPR cap. (512,4) capped VGPRs at 64 and spilled the
// prefetch buffers to scratch: 465 MB of scratch writes, 2.2x slowdown.
#define TILE_H 8
__global__ __launch_bounds__(512, 2) void k_vote(const float* __restrict__ input,
                                                 const float* __restrict__ a,
                                                 const float* __restrict__ b,
                                                 int* __restrict__ ws) {
    __shared__ int   hist_s[TSZ];   // 32 KB
    __shared__ float a_s[AL];
    const int tid = threadIdx.x;

    for (int i = tid; i < TSZ; i += 512) hist_s[i] = 0;
    for (int i = tid; i < AL; i += 512) a_s[i] = a[i];
    __syncthreads();

    const float bv = b[0];
    // swizzle: xcd = blockIdx&7 gets 64 consecutive tiles (2 whole images)
    const int t   = (blockIdx.x & 7) * 64 + (blockIdx.x >> 3);
    const int by  = t & 31;                // 32 row-tiles per image
    const int n   = t >> 5;                // 16 images
    const int y0  = by * TILE_H;
    const int lane = tid & 63;             // wave spans full 256-px row
    const int wv  = tid >> 6;              // 8 waves = 8 rows
    const int x4  = lane * 4;              // columns x4..x4+3
    const int y   = y0 + wv;               // output row

    float acc[4] = {0.f, 0.f, 0.f, 0.f};
    const float* imgbase = input + (size_t)n * C_CH * HH * WW;
    const bool hasL = (lane > 0), hasR = (lane < 63);

    float4 vbuf[4][3];          // center 4 px
    float  lbuf[4][3];          // halo x4-1
    float  rbuf[4][3];          // halo x4+4

    #pragma unroll
    for (int cc = 0; cc < 2; ++cc) {       // preload channels 0,1
        const float* src = imgbase + (size_t)cc * (HH * WW);
        #pragma unroll
        for (int r = 0; r < 3; ++r) {      // input rows y-1 .. y+1
            int gy = y - 1 + r;
            bool ok = (gy >= 0 && gy < HH);
            const float* rp = src + gy * WW;
            vbuf[cc][r] = ok ? *(const float4*)(rp + x4)
                             : make_float4(0.f, 0.f, 0.f, 0.f);
            lbuf[cc][r] = (ok && hasL) ? rp[x4 - 1] : 0.f;
            rbuf[cc][r] = (ok && hasR) ? rp[x4 + 4] : 0.f;
        }
    }

    #pragma unroll 4
    for (int c = 0; c < C_CH; ++c) {
        const int cur = c & 3;
        if (c + 2 < C_CH) {                // prefetch 2 channels ahead
            const float* src = imgbase + (size_t)(c + 2) * (HH * WW);
            const int nx = (c + 2) & 3;
            #pragma unroll
            for (int r = 0; r < 3; ++r) {
                int gy = y - 1 + r;
                bool ok = (gy >= 0 && gy < HH);
                const float* rp = src + gy * WW;
                vbuf[nx][r] = ok ? *(const float4*)(rp + x4)
                                 : make_float4(0.f, 0.f, 0.f, 0.f);
                lbuf[nx][r] = (ok && hasL) ? rp[x4 - 1] : 0.f;
                rbuf[nx][r] = (ok && hasR) ? rp[x4 + 4] : 0.f;
            }
        }
        const float* ac = a_s + c * 9;
        #pragma unroll
        for (int r = 0; r < 3; ++r) {      // r == ky
            const float4 v = vbuf[cur][r];
            const float w[6] = {lbuf[cur][r], v.x, v.y, v.z, v.w, rbuf[cur][r]};
            #pragma unroll
            for (int p = 0; p < 4; ++p)
                #pragma unroll
                for (int kx = 0; kx < 3; ++kx)
                    acc[p] += w[p + kx] * ac[r * 3 + kx];
        }
    }

    // constant Q-channel (0.5 inside image, zero-padded) + vote
    {
        int gy = y;
        #pragma unroll
        for (int p = 0; p < 4; ++p) {
            int gx = x4 + p;
            float cs = 0.f;
            #pragma unroll
            for (int ky = 0; ky < 3; ++ky) {
                int yy = gy + ky - 1;
                if (yy < 0 || yy >= HH) continue;
                #pragma unroll
                for (int kx = 0; kx < 3; ++kx) {
                    int xx = gx + kx - 1;
                    if (xx < 0 || xx >= WW) continue;
                    cs += a_s[FLATK + ky * 3 + kx];
                }
            }
            float tt = acc[p] + 0.5f * cs;
            float v = floorf((tt + bv) / RADIUS);
            int vi = (int)fabsf(fmodf(v, (float)TSZ));
            atomicAdd(&hist_s[vi], 1);
        }
    }

    __syncthreads();
    int* hist_g = ws + WS_HIST;
    for (int i = tid; i < TSZ; i += 512) {
        int v = hist_s[i];
        if (v) atomicAdd(&hist_g[i], v);
    }
}

// ---------------- K3: parallel argmax (32 blocks) + count output ----------
// key = count<<13 | (8191 - idx): max key => max count, tie => smallest idx
// (matches jnp.argmax first-occurrence semantics).
__global__ __launch_bounds__(256) void k_argmax(const int* __restrict__ ws,
                                                int* __restrict__ wsbest,
                                                float* __restrict__ out) {
    const int tid = threadIdx.x;
    const int t = blockIdx.x * 256 + tid;
    const int v = ws[WS_HIST + t];
    out[512 * FLATK + t] = (float)v;      // count output (coalesced)

    unsigned long long key =
        ((unsigned long long)(unsigned)v << 13) | (unsigned)(TSZ - 1 - t);
    #pragma unroll
    for (int off = 32; off > 0; off >>= 1) {
        unsigned long long o = __shfl_xor(key, off);
        if (o > key) key = o;
    }
    __shared__ unsigned long long wk[4];
    const int lane = tid & 63, wvi = tid >> 6;
    if (lane == 0) wk[wvi] = key;
    __syncthreads();
    if (tid == 0) {
        unsigned long long k = wk[0];
        for (int i = 1; i < 4; ++i) if (wk[i] > k) k = wk[i];
        atomicMax((unsigned long long*)(wsbest + WS_BEST), k);
    }
}

// ---------------- K3b: decode best, index output, active row list ---------
__global__ __launch_bounds__(256) void k_rows(int* __restrict__ ws,
                                              float* __restrict__ out) {
    __shared__ int wsum[4];
    const int tid = threadIdx.x;
    const unsigned long long key = *(const unsigned long long*)(ws + WS_BEST);
    const int bestIdx = (TSZ - 1) - (int)(key & (unsigned long long)(TSZ - 1));
    if (tid == 0) out[512 * FLATK + TSZ] = (float)bestIdx;

    // active rows via ballot prefix-scan (insertion order = ascending id)
    int* rows = ws + WS_ROWS;
    for (int i = tid; i < 2 * O_CH; i += 256) rows[i] = -1;
    const int o = tid;
    const int match = (ws[WS_KIDX + o] == bestIdx) ? 1 : 0;
    unsigned long long m = __ballot(match);
    const int lane = tid & 63, wvi = tid >> 6;
    if (lane == 0) wsum[wvi] = __popcll(m);
    __syncthreads();   // also orders the -1 fill before the scatter
    int prefix = 0;
    for (int i = 0; i < wvi; ++i) prefix += wsum[i];
    int before = __popcll(m & ((1ull << lane) - 1ull));
    if (match) rows[prefix + before] = o;
}

// ---------------- K4: gather active kernels (float4) ----------------
__global__ __launch_bounds__(256) void k_gather(const float* __restrict__ kernels,
                                                const int* __restrict__ ws,
                                                float* __restrict__ out) {
    int gid = blockIdx.x * 256 + threadIdx.x;        // 512*144 = 73728 total
    if (gid >= 2 * O_CH * (FLATK / 4)) return;
    int s = gid / (FLATK / 4);
    int j = gid - s * (FLATK / 4);
    int r = ws[WS_ROWS + s];
    float4 v = (r >= 0) ? *(const float4*)(kernels + r * FLATK + j * 4)
                        : make_float4(0.f, 0.f, 0.f, 0.f);
    *((float4*)out + gid) = v;
}

extern "C" void kernel_launch(void* const* d_in, const int* in_sizes, int n_in,
                              void* d_out, int out_size, void* d_ws, size_t ws_size,
                              hipStream_t stream) {
    const float* input   = (const float*)d_in[0];
    const float* kernels = (const float*)d_in[1];
    const float* a       = (const float*)d_in[2];
    const float* b       = (const float*)d_in[3];
    float* out = (float*)d_out;
    int*   ws  = (int*)d_ws;

    k_init<<<96, 256, 0, stream>>>(kernels, a, b, ws);
    k_vote<<<NB * (HH / TILE_H), 512, 0, stream>>>(input, a, b, ws);
    k_argmax<<<TSZ / 256, 256, 0, stream>>>(ws, ws, out);
    k_rows<<<1, 256, 0, stream>>>(ws, out);
    k_gather<<<(2 * O_CH * (FLATK / 4) + 255) / 256, 256, 0, stream>>>(kernels, ws, out);
}

// Round 4
// 380.227 us; speedup vs baseline: 1.6068x; 1.2152x over previous
//
#include <hip/hip_runtime.h>

// ALSH conv setup: hash kernels, vote via 1-channel conv, histogram, argmax,
// gather active kernel set.
#define O_CH   256      // out_channels
#define C_CH   64       // in_channels
#define FLATK  576      // C*K*K
#define M_TERMS 9
#define AL     585      // D*K*K = (C + 1)*9
#define TSZ    8192     // table size
#define RADIUS 4.0f
#define NB     16
#define HH     256
#define WW     256

// workspace layout (ints):
//   [0, 256)            k_idx : bucket of each kernel
//   [256, 256+8192)     hist  : vote histogram
//   [8448, 8450)        best  : 64-bit argmax key (count<<13 | (8191-idx))
//   [8450, 8450+512)    rows  : active kernel ids (-1 = empty slot)
#define WS_KIDX 0
#define WS_HIST 256
#define WS_BEST (256 + TSZ)
#define WS_ROWS (256 + TSZ + 2)

// ---------------- K1: hash kernels (1 wave per kernel) + zero histogram ----
__global__ __launch_bounds__(256) void k_init(const float* __restrict__ kernels,
                                              const float* __restrict__ a,
                                              const float* __restrict__ b,
                                              int* __restrict__ ws) {
    if (blockIdx.x < 64) {
        const int wv = threadIdx.x >> 6, lane = threadIdx.x & 63;
        const int o = blockIdx.x * 4 + wv;
        const float* wp = kernels + o * FLATK;
        float dot = 0.f, n2 = 0.f;
        #pragma unroll
        for (int j0 = 0; j0 < FLATK; j0 += 64) {   // 576/64 = 9 coalesced rounds
            float x = wp[j0 + lane];
            dot += x * a[j0 + lane];
            n2  += x * x;
        }
        #pragma unroll
        for (int off = 32; off > 0; off >>= 1) {
            dot += __shfl_xor(dot, off);
            n2  += __shfl_xor(n2, off);
        }
        if (lane == 0) {
            float p = n2, d = dot;
            for (int i = 0; i < M_TERMS; ++i) { d += p * a[FLATK + i]; p *= n2; }
            float hk = floorf((d + b[0]) / RADIUS);
            ws[WS_KIDX + o] = (int)fabsf(fmodf(hk, (float)TSZ));
        }
    } else {
        int t = (blockIdx.x - 64) * 256 + threadIdx.x;
        ws[WS_HIST + t] = 0;
        if (blockIdx.x == 64 && threadIdx.x < 2) ws[WS_BEST + threadIdx.x] = 0;
    }
}

// ---------------- K2: fused vote conv, TILE_H=8, 512 threads --------------
// Block: 512 threads = 8 waves; each wave owns ONE 256-px row (4 px/lane).
// Grid 512. The kernel is latency-bound (VALUBusy ~20%, HBM ~10%), so the
// lever is RESIDENT WAVES: VGPR must stay <= 64 for 2 blocks/CU
// (measured: VGPR=88 -> 1 block/CU, 22.5% occ, 192us; VGPR=64 -> 2 blocks,
// 44% occ). So: shfl halo (no halo regs), dist-1 prefetch with 2-slot
// rotation (vbuf = float4[2][3] = 24 regs), __launch_bounds__(512,4) to pin
// the 64-VGPR cap. Per-pixel FMA order (c -> ky -> p -> kx) unchanged.
#define TILE_H 8
__global__ __launch_bounds__(512, 4) void k_vote(const float* __restrict__ input,
                                                 const float* __restrict__ a,
                                                 const float* __restrict__ b,
                                                 int* __restrict__ ws) {
    __shared__ int   hist_s[TSZ];   // 32 KB
    __shared__ float a_s[AL];
    const int tid = threadIdx.x;

    for (int i = tid; i < TSZ; i += 512) hist_s[i] = 0;
    for (int i = tid; i < AL; i += 512) a_s[i] = a[i];
    __syncthreads();

    const float bv = b[0];
    // swizzle: xcd = blockIdx&7 gets 64 consecutive tiles (2 whole images)
    const int t   = (blockIdx.x & 7) * 64 + (blockIdx.x >> 3);
    const int by  = t & 31;                // 32 row-tiles per image
    const int n   = t >> 5;                // 16 images
    const int y0  = by * TILE_H;
    const int lane = tid & 63;             // wave spans full 256-px row
    const int wv  = tid >> 6;              // 8 waves = 8 rows
    const int x4  = lane * 4;              // columns x4..x4+3
    const int y   = y0 + wv;               // output row

    float acc[4] = {0.f, 0.f, 0.f, 0.f};
    const float* imgbase = input + (size_t)n * C_CH * HH * WW;

    float4 vbuf[2][3];
    {
        const float* src = imgbase;        // preload channel 0
        #pragma unroll
        for (int r = 0; r < 3; ++r) {      // input rows y-1 .. y+1
            int gy = y - 1 + r;
            vbuf[0][r] = (gy >= 0 && gy < HH)
                       ? *(const float4*)(src + gy * WW + x4)
                       : make_float4(0.f, 0.f, 0.f, 0.f);
        }
    }

    #pragma unroll 2
    for (int c = 0; c < C_CH; ++c) {
        const int cur = c & 1, nxt = cur ^ 1;
        if (c + 1 < C_CH) {                // prefetch next channel's rows
            const float* src = imgbase + (size_t)(c + 1) * (HH * WW);
            #pragma unroll
            for (int r = 0; r < 3; ++r) {
                int gy = y - 1 + r;
                vbuf[nxt][r] = (gy >= 0 && gy < HH)
                             ? *(const float4*)(src + gy * WW + x4)
                             : make_float4(0.f, 0.f, 0.f, 0.f);
            }
        }
        const float* ac = a_s + c * 9;
        #pragma unroll
        for (int r = 0; r < 3; ++r) {      // r == ky
            float4 v = vbuf[cur][r];
            float lv = __shfl_up(v.w, 1);   if (lane == 0)  lv = 0.f;
            float rv = __shfl_down(v.x, 1); if (lane == 63) rv = 0.f;
            const float w[6] = {lv, v.x, v.y, v.z, v.w, rv};
            #pragma unroll
            for (int p = 0; p < 4; ++p)
                #pragma unroll
                for (int kx = 0; kx < 3; ++kx)
                    acc[p] += w[p + kx] * ac[r * 3 + kx];
        }
    }

    // constant Q-channel (0.5 inside image, zero-padded) + vote
    {
        int gy = y;
        #pragma unroll
        for (int p = 0; p < 4; ++p) {
            int gx = x4 + p;
            float cs = 0.f;
            #pragma unroll
            for (int ky = 0; ky < 3; ++ky) {
                int yy = gy + ky - 1;
                if (yy < 0 || yy >= HH) continue;
                #pragma unroll
                for (int kx = 0; kx < 3; ++kx) {
                    int xx = gx + kx - 1;
                    if (xx < 0 || xx >= WW) continue;
                    cs += a_s[FLATK + ky * 3 + kx];
                }
            }
            float tt = acc[p] + 0.5f * cs;
            float v = floorf((tt + bv) / RADIUS);
            int vi = (int)fabsf(fmodf(v, (float)TSZ));
            atomicAdd(&hist_s[vi], 1);
        }
    }

    __syncthreads();
    int* hist_g = ws + WS_HIST;
    for (int i = tid; i < TSZ; i += 512) {
        int v = hist_s[i];
        if (v) atomicAdd(&hist_g[i], v);
    }
}

// ---------------- K3: parallel argmax (32 blocks) + count output ----------
// key = count<<13 | (8191 - idx): max key => max count, tie => smallest idx
// (matches jnp.argmax first-occurrence semantics).
__global__ __launch_bounds__(256) void k_argmax(const int* __restrict__ ws,
                                                int* __restrict__ wsbest,
                                                float* __restrict__ out) {
    const int tid = threadIdx.x;
    const int t = blockIdx.x * 256 + tid;
    const int v = ws[WS_HIST + t];
    out[512 * FLATK + t] = (float)v;      // count output (coalesced)

    unsigned long long key =
        ((unsigned long long)(unsigned)v << 13) | (unsigned)(TSZ - 1 - t);
    #pragma unroll
    for (int off = 32; off > 0; off >>= 1) {
        unsigned long long o = __shfl_xor(key, off);
        if (o > key) key = o;
    }
    __shared__ unsigned long long wk[4];
    const int lane = tid & 63, wvi = tid >> 6;
    if (lane == 0) wk[wvi] = key;
    __syncthreads();
    if (tid == 0) {
        unsigned long long k = wk[0];
        for (int i = 1; i < 4; ++i) if (wk[i] > k) k = wk[i];
        atomicMax((unsigned long long*)(wsbest + WS_BEST), k);
    }
}

// ---------------- K3b: decode best, index output, active row list ---------
__global__ __launch_bounds__(256) void k_rows(int* __restrict__ ws,
                                              float* __restrict__ out) {
    __shared__ int wsum[4];
    const int tid = threadIdx.x;
    const unsigned long long key = *(const unsigned long long*)(ws + WS_BEST);
    const int bestIdx = (TSZ - 1) - (int)(key & (unsigned long long)(TSZ - 1));
    if (tid == 0) out[512 * FLATK + TSZ] = (float)bestIdx;

    // active rows via ballot prefix-scan (insertion order = ascending id)
    int* rows = ws + WS_ROWS;
    for (int i = tid; i < 2 * O_CH; i += 256) rows[i] = -1;
    const int o = tid;
    const int match = (ws[WS_KIDX + o] == bestIdx) ? 1 : 0;
    unsigned long long m = __ballot(match);
    const int lane = tid & 63, wvi = tid >> 6;
    if (lane == 0) wsum[wvi] = __popcll(m);
    __syncthreads();   // also orders the -1 fill before the scatter
    int prefix = 0;
    for (int i = 0; i < wvi; ++i) prefix += wsum[i];
    int before = __popcll(m & ((1ull << lane) - 1ull));
    if (match) rows[prefix + before] = o;
}

// ---------------- K4: gather active kernels (float4) ----------------
__global__ __launch_bounds__(256) void k_gather(const float* __restrict__ kernels,
                                                const int* __restrict__ ws,
                                                float* __restrict__ out) {
    int gid = blockIdx.x * 256 + threadIdx.x;        // 512*144 = 73728 total
    if (gid >= 2 * O_CH * (FLATK / 4)) return;
    int s = gid / (FLATK / 4);
    int j = gid - s * (FLATK / 4);
    int r = ws[WS_ROWS + s];
    float4 v = (r >= 0) ? *(const float4*)(kernels + r * FLATK + j * 4)
                        : make_float4(0.f, 0.f, 0.f, 0.f);
    *((float4*)out + gid) = v;
}

extern "C" void kernel_launch(void* const* d_in, const int* in_sizes, int n_in,
                              void* d_out, int out_size, void* d_ws, size_t ws_size,
                              hipStream_t stream) {
    const float* input   = (const float*)d_in[0];
    const float* kernels = (const float*)d_in[1];
    const float* a       = (const float*)d_in[2];
    const float* b       = (const float*)d_in[3];
    float* out = (float*)d_out;
    int*   ws  = (int*)d_ws;

    k_init<<<96, 256, 0, stream>>>(kernels, a, b, ws);
    k_vote<<<NB * (HH / TILE_H), 512, 0, stream>>>(input, a, b, ws);
    k_argmax<<<TSZ / 256, 256, 0, stream>>>(ws, ws, out);
    k_rows<<<1, 256, 0, stream>>>(ws, out);
    k_gather<<<(2 * O_CH * (FLATK / 4) + 255) / 256, 256, 0, stream>>>(kernels, ws, out);
}